// Round 13
// baseline (550.704 us; speedup 1.0000x reference)
//
#include <hip/hip_runtime.h>
#include <hip/hip_bf16.h>
#include <stdint.h>

#define TSTEPS 4

typedef __bf16 bf16_t;
typedef __attribute__((ext_vector_type(8))) __bf16 bf16x8;
typedef __attribute__((ext_vector_type(16))) float f32x16;

union frag_u { bf16x8 v; uint32_t d[4]; unsigned short u[8]; };

// gfx9 s_waitcnt immediates: vmcnt low4 [3:0] hi2 [15:14]; expcnt=7,lgkm=15 off
#define VMCNT5  0xF75
#define VMCNT0  0xF70

// ---------------------------------------------------------------------------
// Spike bitmask layout: [m_blk32][kb16][row0..31] -> ushort4 (one ushort per
// timestep; bit j = spike at k-offset j within the 16-wide kb). 4 MB for a
// full [4][8192][1024] spike tensor (16x smaller than bf16).
// GEMM expands bytes of these masks to exact 0/1 bf16 fragments in-register,
// so MFMA inputs are bitwise-identical to the bf16-stored version.
// ---------------------------------------------------------------------------

// ---------------------------------------------------------------------------
// Stage 1: input LIF encoder -> spike bitmasks. C=128. XLA-exact LIF.
// One thread per (m_blk, kb, row): reads 16 contiguous floats, writes ushort4.
// ---------------------------------------------------------------------------
__global__ void spike_encode_mask(const float* __restrict__ x,
                                  unsigned long long* __restrict__ s1)
{
    const int C = 128;
    int tid = blockIdx.x * blockDim.x + threadIdx.x;  // 65536 = 256*8*32
    int row = tid & 31;
    int kb  = (tid >> 5) & 7;
    int m_blk = tid >> 8;
    int m = m_blk * 32 + row;
    const float* px = x + (size_t)m * C + kb * 16;
    float xv[16];
#pragma unroll
    for (int j = 0; j < 16; j += 4) {
        float4 t4 = *(const float4*)(px + j);
        xv[j] = t4.x; xv[j+1] = t4.y; xv[j+2] = t4.z; xv[j+3] = t4.w;
    }
    float v[16];
#pragma unroll
    for (int j = 0; j < 16; ++j) v[j] = 0.0f;
    unsigned long long packed = 0ull;
#pragma unroll
    for (int t = 0; t < TSTEPS; ++t) {
        unsigned int mask = 0;
#pragma unroll
        for (int j = 0; j < 16; ++j) {
            float vv = __fadd_rn(v[j], __fmul_rn(__fsub_rn(xv[j], v[j]), 0.5f));
            bool sp = (vv >= 1.0f);
            mask |= sp ? (1u << j) : 0u;
            v[j] = sp ? 0.0f : vv;
        }
        packed |= (unsigned long long)mask << (16 * t);
    }
    s1[tid] = packed;   // index = (m_blk*8 + kb)*32 + row
}

// ---------------------------------------------------------------------------
// Weight prep: W [K][N] fp32 -> hi/lo bf16 split in B-frag layout (unchanged).
// ---------------------------------------------------------------------------
__global__ void split_transpose_all(const float* __restrict__ enc_W,
                                    const float* __restrict__ W_cells,
                                    bf16_t* __restrict__ W1h, bf16_t* __restrict__ W1l,
                                    bf16_t* __restrict__ W2h, bf16_t* __restrict__ W2l,
                                    bf16_t* __restrict__ W3h, bf16_t* __restrict__ W3l)
{
    const int N = 1024;
    const float* W;
    bf16_t *hi, *lo;
    int K;
    if (blockIdx.z == 0) {
        if (blockIdx.x >= 4) return;
        W = enc_W; hi = W1h; lo = W1l; K = 128;
    } else if (blockIdx.z == 1) {
        W = W_cells; hi = W2h; lo = W2l; K = 1024;
    } else {
        W = W_cells + (size_t)1024 * 1024; hi = W3h; lo = W3l; K = 1024;
    }
    const int NKB = K >> 4;
    __shared__ float tile[32][33];
    int k0 = blockIdx.x * 32, n0 = blockIdx.y * 32;
    int tx = threadIdx.x & 31, ty = threadIdx.x >> 5;
    for (int kk = ty; kk < 32; kk += 8)
        tile[kk][tx] = W[(size_t)(k0 + kk) * N + n0 + tx];
    __syncthreads();
    for (int nn = ty; nn < 32; nn += 8) {
        float wv = tile[tx][nn];
        bf16_t h = (bf16_t)wv;
        bf16_t l = (bf16_t)(wv - (float)h);
        int n = n0 + nn, k = k0 + tx;
        size_t o = ((size_t)(n >> 5) * NKB + (k >> 4)) * 512
                 + (size_t)((n & 31) + ((k >> 3) & 1) * 32) * 8 + (k & 7);
        hi[o] = h;
        lo[o] = l;
    }
}

// ---------------------------------------------------------------------------
// Fused MFMA GEMM + multistep LIF.  R13: bitmask spikes.
// A = spike bitmasks (8 B/lane/kb16 covers all 4 t); B = hi/lo bf16 frag-order.
// Block: 256 thr, 4 waves of 32m x 64n -> 64m x 128n tile; tau=4;
// acc[4t][2nb] f32x16 (128 AGPR). Ring-2, vmcnt(5), no LDS, no barriers.
// Per kb16: 5 loads (1 mask + 4 B) -> expand 4 A-frags from mask bytes
// (bit j -> bf16 1.0/0.0, exact) -> 16 MFMAs (R12's exact order ->
// bitwise-identical accumulators -> absmax 0.0 preserved).
// Epilogue: LIF t-scan; spike bits repacked via __ballot (bits[0:16)=row r0
// cols 0-15 etc.) into next layer's mask layout; LAST: popcount -> Out.
// ---------------------------------------------------------------------------
template <int K, bool LAST>
__global__ __launch_bounds__(256, 2)
void gemm_lif_mfma(const unsigned long long* __restrict__ Amask,
                   const bf16_t* __restrict__ Bh,
                   const bf16_t* __restrict__ Bl,
                   const float* __restrict__ bias,
                   unsigned short* __restrict__ Smask,
                   float* __restrict__ Out,
                   int M, int N)
{
    constexpr int NKB = K >> 4;                 // 8 or 64 (even)

    const int tid = threadIdx.x;
    const int lane = tid & 63;
    const int wid = tid >> 6;
    const int l31 = lane & 31;
    const int half = lane >> 5;
    const int hshift = half * 8;

    int bid = blockIdx.x;
    const int n_t = bid & 7;                    // 8 n-tiles of 128 (XCD-pinned B)
    const int m_t = bid >> 3;                   // 128 m-tiles of 64
    const int m0 = m_t * 64, n0 = n_t * 128;
    const int wave_m = (wid & 1) * 32;
    const int wave_n = (wid >> 1) * 64;
    const int m_blk = (m0 + wave_m) >> 5;
    const int n_blk = (n0 + wave_n) >> 5;

    const unsigned long long* pM = Amask + (size_t)m_blk * NKB * 32 + l31;
    const bf16_t* pH0 = Bh + (size_t)n_blk * NKB * 512 + lane * 8;
    const bf16_t* pH1 = Bh + (size_t)(n_blk + 1) * NKB * 512 + lane * 8;
    const bf16_t* pL0 = Bl + (size_t)n_blk * NKB * 512 + lane * 8;
    const bf16_t* pL1 = Bl + (size_t)(n_blk + 1) * NKB * 512 + lane * 8;

    f32x16 acc[TSTEPS][2];
#pragma unroll
    for (int t = 0; t < TSTEPS; ++t)
#pragma unroll
        for (int nb = 0; nb < 2; ++nb)
            for (int rr = 0; rr < 16; ++rr) acc[t][nb][rr] = 0.0f;

    unsigned long long fm[2];
    bf16x8 fb[2][4];                            // H0,H1,L0,L1

#define LOADB(kb_, s_) {                                                     \
        const int _o = (kb_) * 512;                                          \
        fm[s_] = pM[(size_t)(kb_) * 32];                                     \
        fb[s_][0] = *(const bf16x8*)(pH0 + _o);                              \
        fb[s_][1] = *(const bf16x8*)(pH1 + _o);                              \
        fb[s_][2] = *(const bf16x8*)(pL0 + _o);                              \
        fb[s_][3] = *(const bf16x8*)(pL1 + _o);                              \
    }

#define EXPAND(mb_, f_) {                                                    \
        (f_).d[0] = (((mb_) & 1u)   ? 0x3F80u : 0u) | (((mb_) & 2u)   ? 0x3F800000u : 0u); \
        (f_).d[1] = (((mb_) & 4u)   ? 0x3F80u : 0u) | (((mb_) & 8u)   ? 0x3F800000u : 0u); \
        (f_).d[2] = (((mb_) & 16u)  ? 0x3F80u : 0u) | (((mb_) & 32u)  ? 0x3F800000u : 0u); \
        (f_).d[3] = (((mb_) & 64u)  ? 0x3F80u : 0u) | (((mb_) & 128u) ? 0x3F800000u : 0u); \
    }

// R12's exact MFMA order (hi pass over 8 accs, then lo pass) with A-frags
// expanded from mask bytes. Per-acc hi@kb then lo@kb, kb ascending.
#define MFMASTEP(s_) {                                                       \
        uint32_t _lo = (uint32_t)fm[s_], _hi = (uint32_t)(fm[s_] >> 32);     \
        frag_u af0, af1, af2, af3;                                           \
        EXPAND((_lo >> hshift) & 0xFFu, af0);                                \
        EXPAND((_lo >> (16 + hshift)) & 0xFFu, af1);                         \
        EXPAND((_hi >> hshift) & 0xFFu, af2);                                \
        EXPAND((_hi >> (16 + hshift)) & 0xFFu, af3);                         \
        acc[0][0] = __builtin_amdgcn_mfma_f32_32x32x16_bf16(af0.v, fb[s_][0], acc[0][0], 0, 0, 0); \
        acc[1][0] = __builtin_amdgcn_mfma_f32_32x32x16_bf16(af1.v, fb[s_][0], acc[1][0], 0, 0, 0); \
        acc[2][0] = __builtin_amdgcn_mfma_f32_32x32x16_bf16(af2.v, fb[s_][0], acc[2][0], 0, 0, 0); \
        acc[3][0] = __builtin_amdgcn_mfma_f32_32x32x16_bf16(af3.v, fb[s_][0], acc[3][0], 0, 0, 0); \
        acc[0][1] = __builtin_amdgcn_mfma_f32_32x32x16_bf16(af0.v, fb[s_][1], acc[0][1], 0, 0, 0); \
        acc[1][1] = __builtin_amdgcn_mfma_f32_32x32x16_bf16(af1.v, fb[s_][1], acc[1][1], 0, 0, 0); \
        acc[2][1] = __builtin_amdgcn_mfma_f32_32x32x16_bf16(af2.v, fb[s_][1], acc[2][1], 0, 0, 0); \
        acc[3][1] = __builtin_amdgcn_mfma_f32_32x32x16_bf16(af3.v, fb[s_][1], acc[3][1], 0, 0, 0); \
        acc[0][0] = __builtin_amdgcn_mfma_f32_32x32x16_bf16(af0.v, fb[s_][2], acc[0][0], 0, 0, 0); \
        acc[1][0] = __builtin_amdgcn_mfma_f32_32x32x16_bf16(af1.v, fb[s_][2], acc[1][0], 0, 0, 0); \
        acc[2][0] = __builtin_amdgcn_mfma_f32_32x32x16_bf16(af2.v, fb[s_][2], acc[2][0], 0, 0, 0); \
        acc[3][0] = __builtin_amdgcn_mfma_f32_32x32x16_bf16(af3.v, fb[s_][2], acc[3][0], 0, 0, 0); \
        acc[0][1] = __builtin_amdgcn_mfma_f32_32x32x16_bf16(af0.v, fb[s_][3], acc[0][1], 0, 0, 0); \
        acc[1][1] = __builtin_amdgcn_mfma_f32_32x32x16_bf16(af1.v, fb[s_][3], acc[1][1], 0, 0, 0); \
        acc[2][1] = __builtin_amdgcn_mfma_f32_32x32x16_bf16(af2.v, fb[s_][3], acc[2][1], 0, 0, 0); \
        acc[3][1] = __builtin_amdgcn_mfma_f32_32x32x16_bf16(af3.v, fb[s_][3], acc[3][1], 0, 0, 0); \
    }

#define STEP(kb_, s_) {                                                      \
        if ((kb_) + 1 < NKB) {                                               \
            LOADB((kb_) + 1, (s_) ^ 1);                                      \
            __builtin_amdgcn_s_waitcnt(VMCNT5);                              \
        } else {                                                             \
            __builtin_amdgcn_s_waitcnt(VMCNT0);                              \
        }                                                                    \
        asm volatile("" ::: "memory");                                       \
        MFMASTEP(s_);                                                        \
    }

    LOADB(0, 0);
#pragma unroll 2
    for (int kb = 0; kb < NKB; kb += 2) {
        STEP(kb + 0, 0);
        STEP(kb + 1, 1);
    }

#undef STEP
#undef MFMASTEP
#undef EXPAND
#undef LOADB

    // --- LIF epilogue: t-scan in registers (XLA-exact); ballot-pack spikes ---
    float bv[2] = {bias[n0 + wave_n + l31], bias[n0 + wave_n + 32 + l31]};
    f32x16 vmem[2];
    uint64_t bits[2] = {0ull, 0ull};
#pragma unroll
    for (int nb = 0; nb < 2; ++nb)
        for (int rr = 0; rr < 16; ++rr) vmem[nb][rr] = 0.0f;

    const int NKBo = N >> 4;
    for (int t = 0; t < TSTEPS; ++t) {
        for (int nb = 0; nb < 2; ++nb) {
            const int kbase = (n0 + wave_n + nb * 32) >> 4;
#pragma unroll
            for (int rr = 0; rr < 16; ++rr) {
                float y = __fadd_rn(acc[t][nb][rr], bv[nb]);
                float vv = vmem[nb][rr];
                vv = __fadd_rn(vv, __fmul_rn(__fsub_rn(y, vv), 0.5f));
                bool sp = (vv >= 1.0f);
                vmem[nb][rr] = sp ? 0.0f : vv;
                if (LAST) {
                    bits[nb] |= sp ? (1ull << (rr * 4 + t)) : 0ull;
                } else {
                    unsigned long long b = __ballot(sp);
                    int r0 = (rr & 3) + 8 * (rr >> 2);
                    // bits[0:16)=row r0 cols 0-15, [16:32)=row r0 cols 16-31,
                    // [32:48)=row r0+4 cols 0-15, [48:64)=row r0+4 cols 16-31
                    if (lane == 0) {
                        Smask[(((size_t)m_blk * NKBo + kbase) * 32 + r0) * 4 + t] =
                            (unsigned short)b;
                        Smask[(((size_t)m_blk * NKBo + kbase + 1) * 32 + r0) * 4 + t] =
                            (unsigned short)(b >> 16);
                    } else if (lane == 32) {
                        Smask[(((size_t)m_blk * NKBo + kbase) * 32 + r0 + 4) * 4 + t] =
                            (unsigned short)(b >> 32);
                        Smask[(((size_t)m_blk * NKBo + kbase + 1) * 32 + r0 + 4) * 4 + t] =
                            (unsigned short)(b >> 48);
                    }
                }
            }
        }
    }

    if (LAST) {
#pragma unroll
        for (int nb = 0; nb < 2; ++nb)
#pragma unroll
            for (int rr = 0; rr < 16; ++rr) {
                int m_r = (rr & 3) + 8 * (rr >> 2) + 4 * half;
                int m = m0 + wave_m + m_r;
                int n = n0 + wave_n + nb * 32 + l31;
                int cnt = __popc((unsigned)((bits[nb] >> (rr * 4)) & 0xFull));
                Out[(size_t)m * N + n] = 0.25f * (float)cnt;
            }
    }
}

// ---------------------------------------------------------------------------
// out2[b][d] = mean over L of out[b][l][d]. Exact in fp32 (quarter-integers).
// ---------------------------------------------------------------------------
__global__ void mean_over_L_kernel(const float* __restrict__ out,
                                   float* __restrict__ out2,
                                   int B, int L, int D)
{
    int id = blockIdx.x * blockDim.x + threadIdx.x;
    if (id >= B * D) return;
    int b = id / D, d = id - b * D;
    const float* p = out + (size_t)b * L * D + d;
    float s = 0.0f;
    for (int l = 0; l < L; ++l) s += p[(size_t)l * D];
    out2[id] = s * (1.0f / (float)L);
}

// ---------------------------------------------------------------------------
extern "C" void kernel_launch(void* const* d_in, const int* in_sizes, int n_in,
                              void* d_out, int out_size, void* d_ws, size_t ws_size,
                              hipStream_t stream)
{
    const float* inputs  = (const float*)d_in[0];  // [16,512,128]
    const float* enc_W   = (const float*)d_in[1];  // [128,1024]
    const float* enc_b   = (const float*)d_in[2];  // [1024]
    const float* W_cells = (const float*)d_in[3];  // [2,1024,1024]
    const float* b_cells = (const float*)d_in[4];  // [2,1024]

    const int B = 16, L = 512, C = 128, D = 1024;
    const int M = B * L;  // 8192

    // ws: s1 masks 512KB | W1h/l 0.5MB | W2h/l 4MB | W3h/l 4MB | h0 4MB | h1 4MB
    char* ws = (char*)d_ws;
    size_t off = 0;
    unsigned long long* s1 = (unsigned long long*)(ws + off);
    off += (size_t)(M / 32) * (C / 16) * 32 * 8;
    bf16_t* W1h = (bf16_t*)(ws + off); off += (size_t)C * D * 2;
    bf16_t* W1l = (bf16_t*)(ws + off); off += (size_t)C * D * 2;
    bf16_t* W2h = (bf16_t*)(ws + off); off += (size_t)D * D * 2;
    bf16_t* W2l = (bf16_t*)(ws + off); off += (size_t)D * D * 2;
    bf16_t* W3h = (bf16_t*)(ws + off); off += (size_t)D * D * 2;
    bf16_t* W3l = (bf16_t*)(ws + off); off += (size_t)D * D * 2;
    unsigned long long* h0 = (unsigned long long*)(ws + off);
    off += (size_t)(M / 32) * (D / 16) * 32 * 8;
    unsigned long long* h1 = (unsigned long long*)(ws + off);

    float* out  = (float*)d_out;          // [M, D]
    float* out2 = out + (size_t)M * D;    // [B, D]

    split_transpose_all<<<dim3(32, 32, 3), 256, 0, stream>>>(
        enc_W, W_cells, W1h, W1l, W2h, W2l, W3h, W3l);

    spike_encode_mask<<<256, 256, 0, stream>>>(inputs, s1);

    const int nblocks = (M / 64) * (D / 128);   // 1024
    gemm_lif_mfma<128, false><<<nblocks, 256, 0, stream>>>(
        s1, W1h, W1l, enc_b, (unsigned short*)h0, nullptr, M, D);
    gemm_lif_mfma<1024, false><<<nblocks, 256, 0, stream>>>(
        h0, W2h, W2l, b_cells, (unsigned short*)h1, nullptr, M, D);
    gemm_lif_mfma<1024, true><<<nblocks, 256, 0, stream>>>(
        h1, W3h, W3l, b_cells + D, nullptr, out, M, D);

    mean_over_L_kernel<<<(B * D + 255) / 256, 256, 0, stream>>>(
        out, out2, B, L, D);
}

// Round 14
// 454.564 us; speedup vs baseline: 1.2115x; 1.2115x over previous
//
#include <hip/hip_runtime.h>
#include <hip/hip_bf16.h>
#include <stdint.h>

#define TSTEPS 4

typedef __bf16 bf16_t;
typedef __attribute__((ext_vector_type(8))) __bf16 bf16x8;
typedef __attribute__((ext_vector_type(16))) float f32x16;
typedef __attribute__((ext_vector_type(4))) unsigned short ushort4v;

union frag_u { bf16x8 v; uint32_t d[4]; unsigned short u[8]; };

// gfx9 s_waitcnt immediates: vmcnt low4 [3:0] hi2 [15:14]; expcnt=7,lgkm=15 off
#define VMCNT3  0xF73
#define VMCNT0  0xF70

// ---------------------------------------------------------------------------
// Spike bitmask layout: [m_blk32][kb16][row0..31] -> ushort4 (one ushort per
// timestep; bit j = spike at k-offset j in the 16-wide kb). 4 MB total for
// [4][8192][1024] (16x smaller than bf16). Expanded in-register to exact
// 0/1 bf16 fragments -> MFMA inputs bitwise-identical to bf16 storage.
// ---------------------------------------------------------------------------

// ---------------------------------------------------------------------------
// Stage 1: input LIF encoder -> spike bitmasks. C=128. XLA-exact LIF.
// ---------------------------------------------------------------------------
__global__ void spike_encode_mask(const float* __restrict__ x,
                                  unsigned long long* __restrict__ s1)
{
    const int C = 128;
    int tid = blockIdx.x * blockDim.x + threadIdx.x;  // 65536 = 256*8*32
    int row = tid & 31;
    int kb  = (tid >> 5) & 7;
    int m_blk = tid >> 8;
    int m = m_blk * 32 + row;
    const float* px = x + (size_t)m * C + kb * 16;
    float xv[16];
#pragma unroll
    for (int j = 0; j < 16; j += 4) {
        float4 t4 = *(const float4*)(px + j);
        xv[j] = t4.x; xv[j+1] = t4.y; xv[j+2] = t4.z; xv[j+3] = t4.w;
    }
    float v[16];
#pragma unroll
    for (int j = 0; j < 16; ++j) v[j] = 0.0f;
    unsigned long long packed = 0ull;
#pragma unroll
    for (int t = 0; t < TSTEPS; ++t) {
        unsigned int mask = 0;
#pragma unroll
        for (int j = 0; j < 16; ++j) {
            float vv = __fadd_rn(v[j], __fmul_rn(__fsub_rn(xv[j], v[j]), 0.5f));
            bool sp = (vv >= 1.0f);
            mask |= sp ? (1u << j) : 0u;
            v[j] = sp ? 0.0f : vv;
        }
        packed |= (unsigned long long)mask << (16 * t);
    }
    s1[tid] = packed;   // index = (m_blk*8 + kb)*32 + row
}

// ---------------------------------------------------------------------------
// Weight prep: W [K][N] fp32 -> hi/lo bf16 split in B-frag layout.
// ---------------------------------------------------------------------------
__global__ void split_transpose_all(const float* __restrict__ enc_W,
                                    const float* __restrict__ W_cells,
                                    bf16_t* __restrict__ W1h, bf16_t* __restrict__ W1l,
                                    bf16_t* __restrict__ W2h, bf16_t* __restrict__ W2l,
                                    bf16_t* __restrict__ W3h, bf16_t* __restrict__ W3l)
{
    const int N = 1024;
    const float* W;
    bf16_t *hi, *lo;
    int K;
    if (blockIdx.z == 0) {
        if (blockIdx.x >= 4) return;
        W = enc_W; hi = W1h; lo = W1l; K = 128;
    } else if (blockIdx.z == 1) {
        W = W_cells; hi = W2h; lo = W2l; K = 1024;
    } else {
        W = W_cells + (size_t)1024 * 1024; hi = W3h; lo = W3l; K = 1024;
    }
    const int NKB = K >> 4;
    __shared__ float tile[32][33];
    int k0 = blockIdx.x * 32, n0 = blockIdx.y * 32;
    int tx = threadIdx.x & 31, ty = threadIdx.x >> 5;
    for (int kk = ty; kk < 32; kk += 8)
        tile[kk][tx] = W[(size_t)(k0 + kk) * N + n0 + tx];
    __syncthreads();
    for (int nn = ty; nn < 32; nn += 8) {
        float wv = tile[tx][nn];
        bf16_t h = (bf16_t)wv;
        bf16_t l = (bf16_t)(wv - (float)h);
        int n = n0 + nn, k = k0 + tx;
        size_t o = ((size_t)(n >> 5) * NKB + (k >> 4)) * 512
                 + (size_t)((n & 31) + ((k >> 3) & 1) * 32) * 8 + (k & 7);
        hi[o] = h;
        lo[o] = l;
    }
}

// ---------------------------------------------------------------------------
// Fused MFMA GEMM + multistep LIF.  R14: mask-A + small wave tile + 3 w/SIMD.
// A = spike bitmasks; B = hi/lo bf16 frag-order. Block: 256 thr, 4 waves of
// 32m x 32n (2x2) -> 64x64 tile; tau=4; acc[4t] f32x16 = 64 AGPR only.
// K-loop per kb16: 3 loads (1 mask 8B for all 4 t + hi/lo B 16B) -> ring-2,
// vmcnt(3) -> expand 4 A-frags from mask bytes (exact 0/1 bf16) -> 8 MFMAs.
// ~130 regs/wave -> __launch_bounds__(256,3): 3 waves/SIMD (every prior
// round ran <=2.5 and plateaued at 38-41% MfmaUtil; memory traffic is now
// negligible so TLP is the remaining lever).
// Epilogue: LIF t-scan (XLA-exact, per-acc order == R12/R13 -> absmax 0.0);
// ballot -> wave-private LDS tile -> ONE coalesced ushort4 (8B) store per
// lane (R13's divergent 2B stores caused 137MB RMW write amplification).
// ---------------------------------------------------------------------------
template <int K, bool LAST>
__global__ __launch_bounds__(256, 3)
void gemm_lif_mfma(const unsigned long long* __restrict__ Amask,
                   const bf16_t* __restrict__ Bh,
                   const bf16_t* __restrict__ Bl,
                   const float* __restrict__ bias,
                   unsigned short* __restrict__ Smask,
                   float* __restrict__ Out,
                   int M, int N)
{
    constexpr int NKB = K >> 4;                 // 8 or 64 (even)
    __shared__ __align__(8) unsigned short sh[4][256];   // [wave][row][kb][t] 2KB

    const int tid = threadIdx.x;
    const int lane = tid & 63;
    const int wid = tid >> 6;
    const int l31 = lane & 31;
    const int half = lane >> 5;
    const int hshift = half * 8;

    int bid = blockIdx.x;
    const int n_t = bid & 15;                   // 16 n-tiles of 64 (2 per XCD)
    const int m_t = bid >> 4;                   // 128 m-tiles of 64
    const int m0 = m_t * 64, n0 = n_t * 64;
    const int wave_m = (wid & 1) * 32;
    const int wave_n = (wid >> 1) * 32;
    const int m_blk = (m0 + wave_m) >> 5;
    const int n_blk = (n0 + wave_n) >> 5;

    const unsigned long long* pM = Amask + (size_t)m_blk * NKB * 32 + l31;
    const bf16_t* pH = Bh + (size_t)n_blk * NKB * 512 + lane * 8;
    const bf16_t* pL = Bl + (size_t)n_blk * NKB * 512 + lane * 8;

    f32x16 acc[TSTEPS];
#pragma unroll
    for (int t = 0; t < TSTEPS; ++t)
        for (int rr = 0; rr < 16; ++rr) acc[t][rr] = 0.0f;

    unsigned long long fm[2];
    bf16x8 fh[2], fl[2];

#define LOADB(kb_, s_) {                                                     \
        const int _o = (kb_) * 512;                                          \
        fm[s_] = pM[(size_t)(kb_) * 32];                                     \
        fh[s_] = *(const bf16x8*)(pH + _o);                                  \
        fl[s_] = *(const bf16x8*)(pL + _o);                                  \
    }

#define EXPAND(mb_, f_) {                                                    \
        (f_).d[0] = (((mb_) & 1u)   ? 0x3F80u : 0u) | (((mb_) & 2u)   ? 0x3F800000u : 0u); \
        (f_).d[1] = (((mb_) & 4u)   ? 0x3F80u : 0u) | (((mb_) & 8u)   ? 0x3F800000u : 0u); \
        (f_).d[2] = (((mb_) & 16u)  ? 0x3F80u : 0u) | (((mb_) & 32u)  ? 0x3F800000u : 0u); \
        (f_).d[3] = (((mb_) & 64u)  ? 0x3F80u : 0u) | (((mb_) & 128u) ? 0x3F800000u : 0u); \
    }

// Per-acc sequence hi@kb then lo@kb, kb ascending == R12/R13 (bitwise match).
#define MFMASTEP(s_) {                                                       \
        uint32_t _lo = (uint32_t)fm[s_], _hi = (uint32_t)(fm[s_] >> 32);     \
        frag_u af0, af1, af2, af3;                                           \
        EXPAND((_lo >> hshift) & 0xFFu, af0);                                \
        EXPAND((_lo >> (16 + hshift)) & 0xFFu, af1);                         \
        EXPAND((_hi >> hshift) & 0xFFu, af2);                                \
        EXPAND((_hi >> (16 + hshift)) & 0xFFu, af3);                         \
        acc[0] = __builtin_amdgcn_mfma_f32_32x32x16_bf16(af0.v, fh[s_], acc[0], 0, 0, 0); \
        acc[1] = __builtin_amdgcn_mfma_f32_32x32x16_bf16(af1.v, fh[s_], acc[1], 0, 0, 0); \
        acc[2] = __builtin_amdgcn_mfma_f32_32x32x16_bf16(af2.v, fh[s_], acc[2], 0, 0, 0); \
        acc[3] = __builtin_amdgcn_mfma_f32_32x32x16_bf16(af3.v, fh[s_], acc[3], 0, 0, 0); \
        acc[0] = __builtin_amdgcn_mfma_f32_32x32x16_bf16(af0.v, fl[s_], acc[0], 0, 0, 0); \
        acc[1] = __builtin_amdgcn_mfma_f32_32x32x16_bf16(af1.v, fl[s_], acc[1], 0, 0, 0); \
        acc[2] = __builtin_amdgcn_mfma_f32_32x32x16_bf16(af2.v, fl[s_], acc[2], 0, 0, 0); \
        acc[3] = __builtin_amdgcn_mfma_f32_32x32x16_bf16(af3.v, fl[s_], acc[3], 0, 0, 0); \
    }

#define STEP(kb_, s_) {                                                      \
        if ((kb_) + 1 < NKB) {                                               \
            LOADB((kb_) + 1, (s_) ^ 1);                                      \
            __builtin_amdgcn_s_waitcnt(VMCNT3);                              \
        } else {                                                             \
            __builtin_amdgcn_s_waitcnt(VMCNT0);                              \
        }                                                                    \
        asm volatile("" ::: "memory");                                       \
        MFMASTEP(s_);                                                        \
    }

    LOADB(0, 0);
#pragma unroll 2
    for (int kb = 0; kb < NKB; kb += 2) {
        STEP(kb + 0, 0);
        STEP(kb + 1, 1);
    }

#undef STEP
#undef MFMASTEP
#undef EXPAND
#undef LOADB

    // --- LIF epilogue: t-scan in registers (XLA-exact arithmetic) ---
    const float bv = bias[n0 + wave_n + l31];
    f32x16 vmem;
#pragma unroll
    for (int rr = 0; rr < 16; ++rr) vmem[rr] = 0.0f;
    uint64_t bits = 0ull;
    unsigned short* myt = &sh[wid][0];          // [row][kb][t] = [32][2][4]

    const int NKBo = N >> 4;
    const int kbase = (n0 + wave_n) >> 4;

    for (int t = 0; t < TSTEPS; ++t) {
#pragma unroll
        for (int rr = 0; rr < 16; ++rr) {
            float y = __fadd_rn(acc[t][rr], bv);
            float vv = vmem[rr];
            vv = __fadd_rn(vv, __fmul_rn(__fsub_rn(y, vv), 0.5f));
            bool sp = (vv >= 1.0f);
            vmem[rr] = sp ? 0.0f : vv;
            if (LAST) {
                bits |= sp ? (1ull << (rr * 4 + t)) : 0ull;
            } else {
                // ballot: low32 = row r0 (lanes 0-31 = cols), high32 = row r0+4
                unsigned long long b = __ballot(sp);
                if (l31 == 0) {
                    uint32_t hb = (uint32_t)(b >> (half * 32));
                    int rowi = (rr & 3) + 8 * (rr >> 2) + 4 * half;
                    myt[(rowi * 2 + 0) * 4 + t] = (unsigned short)hb;
                    myt[(rowi * 2 + 1) * 4 + t] = (unsigned short)(hb >> 16);
                }
            }
        }
    }

    if (LAST) {
#pragma unroll
        for (int rr = 0; rr < 16; ++rr) {
            int m_r = (rr & 3) + 8 * (rr >> 2) + 4 * half;
            int m = m0 + wave_m + m_r;
            int n = n0 + wave_n + l31;
            int cnt = __popc((unsigned)((bits >> (rr * 4)) & 0xFull));
            Out[(size_t)m * N + n] = 0.25f * (float)cnt;
        }
    } else {
        // one coalesced 8B store per lane: lane -> (row=l31, kb=half)
        ushort4v pk = *(const ushort4v*)&myt[(l31 * 2 + half) * 4];
        *(ushort4v*)(Smask +
            (((size_t)m_blk * NKBo + kbase + half) * 32 + l31) * 4) = pk;
    }
}

// ---------------------------------------------------------------------------
// out2[b][d] = mean over L of out[b][l][d]. Exact in fp32 (quarter-integers).
// ---------------------------------------------------------------------------
__global__ void mean_over_L_kernel(const float* __restrict__ out,
                                   float* __restrict__ out2,
                                   int B, int L, int D)
{
    int id = blockIdx.x * blockDim.x + threadIdx.x;
    if (id >= B * D) return;
    int b = id / D, d = id - b * D;
    const float* p = out + (size_t)b * L * D + d;
    float s = 0.0f;
    for (int l = 0; l < L; ++l) s += p[(size_t)l * D];
    out2[id] = s * (1.0f / (float)L);
}

// ---------------------------------------------------------------------------
extern "C" void kernel_launch(void* const* d_in, const int* in_sizes, int n_in,
                              void* d_out, int out_size, void* d_ws, size_t ws_size,
                              hipStream_t stream)
{
    const float* inputs  = (const float*)d_in[0];  // [16,512,128]
    const float* enc_W   = (const float*)d_in[1];  // [128,1024]
    const float* enc_b   = (const float*)d_in[2];  // [1024]
    const float* W_cells = (const float*)d_in[3];  // [2,1024,1024]
    const float* b_cells = (const float*)d_in[4];  // [2,1024]

    const int B = 16, L = 512, C = 128, D = 1024;
    const int M = B * L;  // 8192

    // ws: s1 masks 512KB | W1h/l 0.5MB | W2h/l 4MB | W3h/l 4MB | h0 4MB | h1 4MB
    char* ws = (char*)d_ws;
    size_t off = 0;
    unsigned long long* s1 = (unsigned long long*)(ws + off);
    off += (size_t)(M / 32) * (C / 16) * 32 * 8;
    bf16_t* W1h = (bf16_t*)(ws + off); off += (size_t)C * D * 2;
    bf16_t* W1l = (bf16_t*)(ws + off); off += (size_t)C * D * 2;
    bf16_t* W2h = (bf16_t*)(ws + off); off += (size_t)D * D * 2;
    bf16_t* W2l = (bf16_t*)(ws + off); off += (size_t)D * D * 2;
    bf16_t* W3h = (bf16_t*)(ws + off); off += (size_t)D * D * 2;
    bf16_t* W3l = (bf16_t*)(ws + off); off += (size_t)D * D * 2;
    unsigned long long* h0 = (unsigned long long*)(ws + off);
    off += (size_t)(M / 32) * (D / 16) * 32 * 8;
    unsigned long long* h1 = (unsigned long long*)(ws + off);

    float* out  = (float*)d_out;          // [M, D]
    float* out2 = out + (size_t)M * D;    // [B, D]

    split_transpose_all<<<dim3(32, 32, 3), 256, 0, stream>>>(
        enc_W, W_cells, W1h, W1l, W2h, W2l, W3h, W3l);

    spike_encode_mask<<<256, 256, 0, stream>>>(inputs, s1);

    const int nblocks = (M / 64) * (D / 64);   // 2048
    gemm_lif_mfma<128, false><<<nblocks, 256, 0, stream>>>(
        s1, W1h, W1l, enc_b, (unsigned short*)h0, nullptr, M, D);
    gemm_lif_mfma<1024, false><<<nblocks, 256, 0, stream>>>(
        h0, W2h, W2l, b_cells, (unsigned short*)h1, nullptr, M, D);
    gemm_lif_mfma<1024, true><<<nblocks, 256, 0, stream>>>(
        h1, W3h, W3l, b_cells + D, nullptr, out, M, D);

    mean_over_L_kernel<<<(B * D + 255) / 256, 256, 0, stream>>>(
        out, out2, B, L, D);
}